// Round 8
// baseline (1148.102 us; speedup 1.0000x reference)
//
#include <hip/hip_runtime.h>

#define DIV_UP(a,b) (((a)+(b)-1)/(b))

typedef float v4f __attribute__((ext_vector_type(4)));
typedef unsigned short us4 __attribute__((ext_vector_type(4)));
typedef __attribute__((ext_vector_type(8))) short bf16x8;
typedef __attribute__((ext_vector_type(4))) float f32x4;

// ---------- non-temporal helpers ----------
__device__ __forceinline__ float4 ntload4(const float* p) {
  v4f v = __builtin_nontemporal_load((const v4f*)p);
  return make_float4(v.x, v.y, v.z, v.w);
}

// ---------- ordered-uint float max keys ----------
__device__ __forceinline__ unsigned f2key(float f) {
  unsigned u = __float_as_uint(f);
  return (u & 0x80000000u) ? ~u : (u | 0x80000000u);
}
__device__ __forceinline__ float key2f(unsigned u) {
  unsigned b = (u & 0x80000000u) ? (u ^ 0x80000000u) : ~u;
  return __uint_as_float(b);
}

// ---------- bf16 pack/unpack (RNE) ----------
__device__ __forceinline__ unsigned short f2bf(float f) {
  unsigned u = __float_as_uint(f);
  unsigned r = u + 0x7FFFu + ((u >> 16) & 1u);
  return (unsigned short)(r >> 16);
}
__device__ __forceinline__ float bf2f(unsigned short s) {
  return __uint_as_float(((unsigned)s) << 16);
}

// ---------- LDS XOR-swizzle (ushort units, 16B chunks) ----------
__device__ __forceinline__ int swz(int row) {
  return ((row ^ (row >> 3)) & 7) << 3;
}

// ---------- scans over cnt4 (4N chunk-counters) -> rowptr4 ----------
__global__ void k_scan1(const int* __restrict__ cnt, int* __restrict__ incl,
                        int* __restrict__ bsum, int M) {
  __shared__ int s[1024];
  int t = threadIdx.x;
  int i = blockIdx.x * 1024 + t;
  int v = (i < M) ? cnt[i] : 0;
  s[t] = v;
  __syncthreads();
  for (int off = 1; off < 1024; off <<= 1) {
    int add = (t >= off) ? s[t - off] : 0;
    __syncthreads();
    s[t] += add;
    __syncthreads();
  }
  if (i < M) incl[i] = s[t];
  if (t == 1023) bsum[blockIdx.x] = s[1023];
}

__global__ void k_scan2(const int* __restrict__ bsum, int* __restrict__ bex, int nb) {
  __shared__ int s[512];
  int t = threadIdx.x;
  if (nb <= 512) {
    int v = (t < nb) ? bsum[t] : 0;
    s[t] = v;
    __syncthreads();
    for (int off = 1; off < 512; off <<= 1) {
      int add = (t >= off) ? s[t - off] : 0;
      __syncthreads();
      s[t] += add;
      __syncthreads();
    }
    if (t < nb) bex[t] = s[t] - v;  // exclusive
  } else if (t == 0) {
    int run = 0;
    for (int b = 0; b < nb; ++b) { bex[b] = run; run += bsum[b]; }
  }
}

// rowptr4 over 4N chunk-slots; dis per row from summed chunk counts
__global__ void k_scan3(const int* __restrict__ incl, const int* __restrict__ cnt4,
                        const int* __restrict__ bex, int* __restrict__ rowptr4,
                        float* __restrict__ dis, int N, int M, int E) {
  int i = blockIdx.x * blockDim.x + threadIdx.x;
  if (i < M) rowptr4[i] = incl[i] - cnt4[i] + bex[i >> 10];
  if (i < N) {
    int4 c4 = *(const int4*)&cnt4[4 * i];
    int c = c4.x + c4.y + c4.z + c4.w;
    dis[i] = (c > 0) ? rsqrtf((float)c) : 0.0f;
  }
  if (i == 0) rowptr4[M] = E;
}

// ---------- shortcut GEMM body (MFMA): Sbf = bf16(x @ W_sc + b_sc) ----------
__device__ __forceinline__ void gemmsc_body(unsigned short* wTsc, unsigned short* x16,
                                            int bid,
                                            const float* __restrict__ X,
                                            const float* __restrict__ W,
                                            const float* __restrict__ bias,
                                            unsigned short* __restrict__ Sbf, int N) {
  int tid = threadIdx.x;
  for (int i4 = tid; i4 < 1024; i4 += 512) {
    int d = i4 >> 4, h4 = i4 & 15;
    float4 v = ((const float4*)W)[i4];
    int colb = h4 * 4;
    wTsc[(colb + 0) * 64 + (d ^ swz(colb + 0))] = f2bf(v.x);
    wTsc[(colb + 1) * 64 + (d ^ swz(colb + 1))] = f2bf(v.y);
    wTsc[(colb + 2) * 64 + (d ^ swz(colb + 2))] = f2bf(v.z);
    wTsc[(colb + 3) * 64 + (d ^ swz(colb + 3))] = f2bf(v.w);
  }
  int rowbase = bid * 128;
  for (int i4 = tid; i4 < 2048; i4 += 512) {
    int r = i4 >> 4, c4 = i4 & 15;
    int row = rowbase + r;
    float4 v = (row < N) ? ntload4(X + (size_t)row * 64 + c4 * 4)
                         : make_float4(0.f, 0.f, 0.f, 0.f);
    us4 pk;
    pk.x = f2bf(v.x); pk.y = f2bf(v.y); pk.z = f2bf(v.z); pk.w = f2bf(v.w);
    *(us4*)&x16[r * 64 + ((c4 * 4) ^ swz(r))] = pk;
  }
  __syncthreads();

  int lane = tid & 63;
  int wv = tid >> 6;
  int lo = lane & 15;
  int hi = lane >> 4;

  f32x4 acc[4];
#pragma unroll
  for (int ct = 0; ct < 4; ++ct) acc[ct] = (f32x4){0.f, 0.f, 0.f, 0.f};

#pragma unroll
  for (int ks = 0; ks < 2; ++ks) {
    int ar = wv * 16 + lo;
    bf16x8 af = *(const bf16x8*)&x16[ar * 64 + ((ks * 32 + hi * 8) ^ swz(ar))];
#pragma unroll
    for (int ct = 0; ct < 4; ++ct) {
      int br = ct * 16 + lo;
      bf16x8 bfr = *(const bf16x8*)&wTsc[br * 64 + ((ks * 32 + hi * 8) ^ swz(br))];
      acc[ct] = __builtin_amdgcn_mfma_f32_16x16x32_bf16(af, bfr, acc[ct], 0, 0, 0);
    }
  }

  float bv[4];
#pragma unroll
  for (int ct = 0; ct < 4; ++ct) bv[ct] = bias[ct * 16 + lo];
  int rowb = rowbase + wv * 16 + hi * 4;
#pragma unroll
  for (int reg = 0; reg < 4; ++reg) {
    int row = rowb + reg;
    if (row < N) {
      size_t o = (size_t)row * 64 + lo;
#pragma unroll
      for (int ct = 0; ct < 4; ++ct)
        __builtin_nontemporal_store(f2bf(acc[ct][reg] + bv[ct]), &Sbf[o + ct * 16]);
    }
  }
}

// ---------- shared MFMA tail for the 128x192 layer GEMM ---------------------
__device__ __forceinline__ void mfma192_tail(const unsigned short* x16,
                                             const unsigned short* wT,
                                             int rowbase, int tid,
                                             const float* __restrict__ bias,
                                             const float* __restrict__ dis,
                                             unsigned short* __restrict__ A02bf,
                                             unsigned short* __restrict__ Y1bf,
                                             unsigned short* __restrict__ Y2bf,
                                             int N) {
  int lane = tid & 63;
  int wv = tid >> 6;
  int lo = lane & 15;
  int hi = lane >> 4;

  f32x4 acc[12];
#pragma unroll
  for (int ct = 0; ct < 12; ++ct) acc[ct] = (f32x4){0.f, 0.f, 0.f, 0.f};

#pragma unroll
  for (int ks = 0; ks < 2; ++ks) {
    int ar = wv * 16 + lo;
    bf16x8 af = *(const bf16x8*)&x16[ar * 64 + ((ks * 32 + hi * 8) ^ swz(ar))];
#pragma unroll
    for (int ct = 0; ct < 12; ++ct) {
      int br = ct * 16 + lo;
      bf16x8 bfr = *(const bf16x8*)&wT[br * 64 + ((ks * 32 + hi * 8) ^ swz(br))];
      acc[ct] = __builtin_amdgcn_mfma_f32_16x16x32_bf16(af, bfr, acc[ct], 0, 0, 0);
    }
  }

  float bv[4];
#pragma unroll
  for (int ct = 0; ct < 4; ++ct) bv[ct] = bias[ct * 16 + lo];
  int rowb = rowbase + wv * 16 + hi * 4;
#pragma unroll
  for (int reg = 0; reg < 4; ++reg) {
    int row = rowb + reg;
    if (row < N) {
      float dn = dis[row];
      size_t o = (size_t)row * 64 + lo;
#pragma unroll
      for (int ct = 0; ct < 4; ++ct) {
        float o0 = acc[ct][reg] + bv[ct];
        float o1 = acc[ct + 4][reg];
        float o2 = acc[ct + 8][reg];
        A02bf[o + ct * 16] = f2bf(o0 - o2);
        Y1bf[o + ct * 16] = f2bf(o1);
        Y2bf[o + ct * 16] = f2bf(dn * o2);
      }
    }
  }
}

__device__ __forceinline__ void stage_wT(unsigned short* wT,
                                         const float* __restrict__ W, int tid) {
  for (int i4 = tid; i4 < 3072; i4 += 512) {
    int k3 = i4 >> 10, rem = i4 & 1023;
    int d = rem >> 4, h4 = rem & 15;
    float4 v = ((const float4*)W)[i4];
    int colb = k3 * 64 + h4 * 4;
    wT[(colb + 0) * 64 + (d ^ swz(colb + 0))] = f2bf(v.x);
    wT[(colb + 1) * 64 + (d ^ swz(colb + 1))] = f2bf(v.y);
    wT[(colb + 2) * 64 + (d ^ swz(colb + 2))] = f2bf(v.z);
    wT[(colb + 3) * 64 + (d ^ swz(colb + 3))] = f2bf(v.w);
  }
}

__device__ __forceinline__ void gemm192_l0_body(unsigned short* x16, unsigned short* wT,
                                                int bid,
                                                const float* __restrict__ X,
                                                const float* __restrict__ W,
                                                const float* __restrict__ bias,
                                                const float* __restrict__ dis,
                                                unsigned short* __restrict__ A02bf,
                                                unsigned short* __restrict__ Y1bf,
                                                unsigned short* __restrict__ Y2bf,
                                                int N) {
  int tid = threadIdx.x;
  stage_wT(wT, W, tid);
  int rowbase = bid * 128;
  for (int i4 = tid; i4 < 2048; i4 += 512) {
    int r = i4 >> 4, c4 = i4 & 15;
    int row = rowbase + r;
    float4 v = (row < N) ? ntload4(X + (size_t)row * 64 + c4 * 4)
                         : make_float4(0.f, 0.f, 0.f, 0.f);
    us4 pk;
    pk.x = f2bf(v.x); pk.y = f2bf(v.y); pk.z = f2bf(v.z); pk.w = f2bf(v.w);
    *(us4*)&x16[r * 64 + ((c4 * 4) ^ swz(r))] = pk;
  }
  __syncthreads();
  mfma192_tail(x16, wT, rowbase, tid, bias, dis, A02bf, Y1bf, Y2bf, N);
}

// ---------- fused A: gemmsc | count+slot (chunked) | sentinel | poolinit ----
// Counts per (row, col-chunk): cnt4[r*4 + (c>>shift)]. One atomic per edge
// (device atomic ceiling ~8/cyc measured r5-r7); eslot = slot within bucket.
__global__ __launch_bounds__(512) void k_fused_a(const float* __restrict__ X,
                                                 const float* __restrict__ W,
                                                 const float* __restrict__ bias,
                                                 unsigned short* __restrict__ Sbf,
                                                 const int* __restrict__ row,
                                                 const int* __restrict__ col,
                                                 int* __restrict__ cnt4,
                                                 int* __restrict__ eslot,
                                                 unsigned short* __restrict__ Y2bf,
                                                 unsigned short* __restrict__ Vbf,
                                                 unsigned* __restrict__ pooled,
                                                 int N, int E, int NBG, int NC,
                                                 int npool, int q, int shift) {
  __shared__ unsigned short wTsc[64 * 64];   // 8 KB
  __shared__ unsigned short x16a[128 * 64];  // 16 KB
  int bid = blockIdx.x;
  bool isg = (bid % q == 0) && (bid / q < NBG);
  if (isg) {
    gemmsc_body(wTsc, x16a, bid / q, X, W, bias, Sbf, N);
  } else {
    int before = min((bid + q - 1) / q, NBG);
    int oi = bid - before;
    if (oi < NC) {
      int e0 = oi * 2048 + threadIdx.x;
      int r[4], c[4], idx[4];
#pragma unroll
      for (int k = 0; k < 4; ++k) {
        int e = e0 + k * 512;
        if (e < E) { r[k] = row[e]; c[k] = col[e]; }
      }
#pragma unroll
      for (int k = 0; k < 4; ++k) {
        int e = e0 + k * 512;
        if (e < E) idx[k] = atomicAdd(&cnt4[r[k] * 4 + (c[k] >> shift)], 1);
      }
#pragma unroll
      for (int k = 0; k < 4; ++k) {
        int e = e0 + k * 512;
        if (e < E) __builtin_nontemporal_store(idx[k], &eslot[e]);
      }
    } else if (oi == NC) {
      if (threadIdx.x < 64) {
        Y2bf[(size_t)N * 64 + threadIdx.x] = 0;
        Vbf[(size_t)N * 64 + threadIdx.x] = 0;
      }
    } else {
      int i = (oi - NC - 1) * 512 + threadIdx.x;
      if (i < npool) pooled[i] = 0x007FFFFFu;  // key(-inf)
    }
  }
}

// ---------- fused B: gemm192(l0, MFMA) | atomic-free chunked fill -----------
__global__ __launch_bounds__(512) void k_fused_b(const float* __restrict__ X,
                                                 const float* __restrict__ W,
                                                 const float* __restrict__ bias,
                                                 const float* __restrict__ dis,
                                                 unsigned short* __restrict__ A02bf,
                                                 unsigned short* __restrict__ Y1bf,
                                                 unsigned short* __restrict__ Y2bf,
                                                 const int* __restrict__ row,
                                                 const int* __restrict__ col,
                                                 const int* __restrict__ rowptr4,
                                                 const int* __restrict__ eslot,
                                                 int* __restrict__ ccol,
                                                 int N, int E, int NBG, int q,
                                                 int shift) {
  __shared__ unsigned short x16b[128 * 64];  // 16 KB
  __shared__ unsigned short wTb[192 * 64];   // 24 KB
  int bid = blockIdx.x;
  bool isg = (bid % q == 0) && (bid / q < NBG);
  if (isg) {
    gemm192_l0_body(x16b, wTb, bid / q, X, W, bias, dis, A02bf, Y1bf, Y2bf, N);
  } else {
    int before = min((bid + q - 1) / q, NBG);
    int oi = bid - before;
    int e0 = oi * 2048 + threadIdx.x;
    int r[4], c[4], sl[4], base[4];
#pragma unroll
    for (int k = 0; k < 4; ++k) {
      int e = e0 + k * 512;
      if (e < E) { r[k] = row[e]; c[k] = col[e]; sl[k] = eslot[e]; }
    }
#pragma unroll
    for (int k = 0; k < 4; ++k) {
      int e = e0 + k * 512;
      if (e < E) base[k] = rowptr4[r[k] * 4 + (c[k] >> shift)];
    }
#pragma unroll
    for (int k = 0; k < 4; ++k) {
      int e = e0 + k * 512;
      if (e < E) ccol[base[k] + sl[k]] = c[k];
    }
  }
}

// ---------- layer GEMM (l>=1): MFMA, bf16 input + in-block BN ---------------
__global__ __launch_bounds__(512) void k_gemm192(
    const unsigned short* __restrict__ Cbf,
    const float* __restrict__ sums, const float* __restrict__ sumsq,
    const float* __restrict__ g, const float* __restrict__ be,
    const float* __restrict__ W, const float* __restrict__ bias,
    const float* __restrict__ dis,
    unsigned short* __restrict__ A02bf, unsigned short* __restrict__ Y1bf,
    unsigned short* __restrict__ Y2bf, int N) {
  __shared__ unsigned short x16[128 * 64];
  __shared__ unsigned short wT[192 * 64];
  int bid = blockIdx.x;
  int tid = threadIdx.x;

  int cb = (tid & 15) * 4;
  float inv_n = 1.0f / (float)N;
  float scv[4], shv[4];
#pragma unroll
  for (int k = 0; k < 4; ++k) {
    float mu = sums[cb + k] * inv_n;
    float var = sumsq[cb + k] * inv_n - mu * mu;
    float sc = g[cb + k] * rsqrtf(var + 1e-5f);
    scv[k] = sc;
    shv[k] = be[cb + k] - mu * sc;
  }

  stage_wT(wT, W, tid);

  int rowbase = bid * 128;
  for (int i4 = tid; i4 < 2048; i4 += 512) {
    int r = i4 >> 4, c4 = i4 & 15;
    int row = rowbase + r;
    float vx, vy, vz, vw;
    if (row < N) {
      unsigned long long u =
          *(const unsigned long long*)(Cbf + (size_t)row * 64 + c4 * 4);
      vx = bf2f((unsigned short)(u & 0xffffu));
      vy = bf2f((unsigned short)((u >> 16) & 0xffffu));
      vz = bf2f((unsigned short)((u >> 32) & 0xffffu));
      vw = bf2f((unsigned short)(u >> 48));
    } else {
      vx = vy = vz = vw = 0.f;
    }
    float a = vx * scv[0] + shv[0];
    float b = vy * scv[1] + shv[1];
    float c = vz * scv[2] + shv[2];
    float d = vw * scv[3] + shv[3];
    a = (a > 0.f) ? a : 0.01f * a;
    b = (b > 0.f) ? b : 0.01f * b;
    c = (c > 0.f) ? c : 0.01f * c;
    d = (d > 0.f) ? d : 0.01f * d;
    us4 pk;
    pk.x = f2bf(a); pk.y = f2bf(b); pk.z = f2bf(c); pk.w = f2bf(d);
    *(us4*)&x16[r * 64 + ((c4 * 4) ^ swz(r))] = pk;
  }
  __syncthreads();

  mfma192_tail(x16, wT, rowbase, tid, bias, dis, A02bf, Y1bf, Y2bf, N);
}

// ---------- prop v9: column-chunk-phased gathers ---------------------------
// CSR bucketed by (row, col-chunk): 4 chunks of <=32K cols (~4MB zbf slice =
// one XCD L2). Phases OUTER, rows INNER: each wave keeps fp32 partials for
// MAXR=7 rows in registers across phases, so during phase p the whole device
// gathers from one L2-resident slice (round-1 evidence: 88MB FETCH/pass =
// L2-thrash on the 12.8MB gather set; chunk slice fits 4MB/XCD L2).
// Per step: each lane loads its quarter's ccol directly (no shfl), one
// dwordx2 gather serves 4 cols x 16 lanes.
// MODE 1: Vbf[n] = bf16( dis[n]*(Y1[n] - 2*dis[n]*acc) ); zeroes stats
// MODE 2: Cbf[n] = bf16( A02[n] - dis[n]*acc )  (+ fused BN stats)
#define MAXR 7
template <int MODE>
__global__ __launch_bounds__(256) void k_prop4(const int* __restrict__ rowptr4,
                                               const int* __restrict__ ccol,
                                               const float* __restrict__ dis,
                                               const unsigned short* __restrict__ zbf,
                                               const unsigned short* __restrict__ inAbf,
                                               unsigned short* __restrict__ outbf,
                                               float* __restrict__ sums,
                                               float* __restrict__ sumsq,
                                               float* __restrict__ zstats,
                                               int N, int nwaves) {
  if (MODE == 1 && blockIdx.x == 0 && threadIdx.x < 128) zstats[threadIdx.x] = 0.f;
  int gw = blockIdx.x * 4 + (threadIdx.x >> 6);
  int lane = threadIdx.x & 63;
  int wid = threadIdx.x >> 6;
  int qtr = lane >> 4;  // quarter: handles cols j+qtr of each 4-col step
  int s = lane & 15;    // sub-lane: owns channels 4s..4s+3 (8 B of a row)
  const unsigned long long* z64 = (const unsigned long long*)zbf;
  const unsigned long long* inA64 = (const unsigned long long*)inAbf;
  unsigned long long* out64 = (unsigned long long*)outbf;
  float st[4] = {0.f, 0.f, 0.f, 0.f}, st2[4] = {0.f, 0.f, 0.f, 0.f};

  for (int n0 = gw; n0 < N; n0 += nwaves * MAXR) {
    float acc[MAXR][4];
#pragma unroll
    for (int ri = 0; ri < MAXR; ++ri) {
      acc[ri][0] = 0.f; acc[ri][1] = 0.f; acc[ri][2] = 0.f; acc[ri][3] = 0.f;
    }
#pragma unroll 1  // phases MUST stay sequential for L2 residency
    for (int ph = 0; ph < 4; ++ph) {
#pragma unroll
      for (int ri = 0; ri < MAXR; ++ri) {
        int n = n0 + ri * nwaves;
        if (n < N) {
          int beg = rowptr4[4 * n + ph];
          int end = rowptr4[4 * n + ph + 1];
          for (int j = beg; j < end; j += 4) {
            int jq = j + qtr;
            int c = ccol[jq];           // alloc padded by 64 -> safe
            c = (jq < end) ? c : N;     // sentinel row N is zeroed
            unsigned long long zv = z64[(size_t)c * 16 + s];
            unsigned d0 = (unsigned)zv, d1 = (unsigned)(zv >> 32);
            acc[ri][0] += __uint_as_float(d0 << 16);
            acc[ri][1] += __uint_as_float(d0 & 0xFFFF0000u);
            acc[ri][2] += __uint_as_float(d1 << 16);
            acc[ri][3] += __uint_as_float(d1 & 0xFFFF0000u);
          }
        }
      }
    }
    // merge quarter partials + epilogue, per row
#pragma unroll
    for (int ri = 0; ri < MAXR; ++ri) {
      int n = n0 + ri * nwaves;
      if (n >= N) continue;  // wave-uniform branch
      float a0 = acc[ri][0], a1 = acc[ri][1], a2 = acc[ri][2], a3 = acc[ri][3];
      a0 += __shfl_xor(a0, 16, 64); a0 += __shfl_xor(a0, 32, 64);
      a1 += __shfl_xor(a1, 16, 64); a1 += __shfl_xor(a1, 32, 64);
      a2 += __shfl_xor(a2, 16, 64); a2 += __shfl_xor(a2, 32, 64);
      a3 += __shfl_xor(a3, 16, 64); a3 += __shfl_xor(a3, 32, 64);
      float dn = dis[n];
      if (qtr == 0) {
        size_t o = (size_t)n * 16 + s;
        unsigned long long av = inA64[o];
        unsigned b0 = (unsigned)av, b1 = (unsigned)(av >> 32);
        float x0 = __uint_as_float(b0 << 16);
        float x1 = __uint_as_float(b0 & 0xFFFF0000u);
        float x2 = __uint_as_float(b1 << 16);
        float x3 = __uint_as_float(b1 & 0xFFFF0000u);
        if (MODE == 1) {
          float v0 = dn * (x0 - 2.f * dn * a0);
          float v1 = dn * (x1 - 2.f * dn * a1);
          float v2 = dn * (x2 - 2.f * dn * a2);
          float v3 = dn * (x3 - 2.f * dn * a3);
          unsigned lo = (unsigned)f2bf(v0) | ((unsigned)f2bf(v1) << 16);
          unsigned hi = (unsigned)f2bf(v2) | ((unsigned)f2bf(v3) << 16);
          out64[o] = (unsigned long long)lo | ((unsigned long long)hi << 32);
        } else {
          float v0 = x0 - dn * a0;
          float v1 = x1 - dn * a1;
          float v2 = x2 - dn * a2;
          float v3 = x3 - dn * a3;
          unsigned lo = (unsigned)f2bf(v0) | ((unsigned)f2bf(v1) << 16);
          unsigned hi = (unsigned)f2bf(v2) | ((unsigned)f2bf(v3) << 16);
          out64[o] = (unsigned long long)lo | ((unsigned long long)hi << 32);
          st[0] += v0; st2[0] = fmaf(v0, v0, st2[0]);
          st[1] += v1; st2[1] = fmaf(v1, v1, st2[1]);
          st[2] += v2; st2[2] = fmaf(v2, v2, st2[2]);
          st[3] += v3; st2[3] = fmaf(v3, v3, st2[3]);
        }
      }
    }
  }
  if (MODE == 2) {
    __shared__ float red[2][4][64];
    if (qtr == 0) {
#pragma unroll
      for (int k = 0; k < 4; ++k) {
        red[0][wid][4 * s + k] = st[k];
        red[1][wid][4 * s + k] = st2[k];
      }
    }
    __syncthreads();
    if (wid == 0) {
      float a = red[0][0][lane] + red[0][1][lane] + red[0][2][lane] + red[0][3][lane];
      float b = red[1][0][lane] + red[1][1][lane] + red[1][2][lane] + red[1][3][lane];
      atomicAdd(&sums[lane], a);
      atomicAdd(&sumsq[lane], b);
    }
  }
}

// fused: h = lrelu(bn(Cbf)) + Sbf; segment-max into pooled (coefs in-block)
__global__ void k_bnpool(const unsigned short* __restrict__ Cbf,
                         const float* __restrict__ sums, const float* __restrict__ sumsq,
                         const float* __restrict__ g, const float* __restrict__ be,
                         const unsigned short* __restrict__ Sbf,
                         const int* __restrict__ batch,
                         unsigned* __restrict__ pooled, int N) {
  __shared__ float sc_s[64], sh_s[64];
  if (threadIdx.x < 64) {
    int h = threadIdx.x;
    float inv_n = 1.0f / (float)N;
    float mu = sums[h] * inv_n;
    float var = sumsq[h] * inv_n - mu * mu;
    float sc = g[h] * rsqrtf(var + 1e-5f);
    sc_s[h] = sc;
    sh_s[h] = be[h] - mu * sc;
  }
  __syncthreads();
  int t = threadIdx.x;
  int h = t & 63;
  int rsub = t >> 6;
  int base = blockIdx.x * 64;
  float sc = sc_s[h], sh = sh_s[h];
  int cur_g = -1;
  unsigned best = 0;
  for (int i = 0; i < 16; ++i) {
    int n = base + rsub + 4 * i;
    if (n >= N) break;
    int gidx = batch[n];
    size_t o = (size_t)n * 64 + h;
    float a = bf2f(__builtin_nontemporal_load(&Cbf[o])) * sc + sh;
    a = (a > 0.f) ? a : 0.01f * a;
    a += bf2f(__builtin_nontemporal_load(&Sbf[o]));
    unsigned k = f2key(a);
    if (gidx != cur_g) {
      if (cur_g >= 0) atomicMax(&pooled[cur_g * 64 + h], best);
      cur_g = gidx;
      best = k;
    } else {
      best = max(best, k);
    }
  }
  if (cur_g >= 0) atomicMax(&pooled[cur_g * 64 + h], best);
}

__global__ void k_final(const unsigned* __restrict__ pooled, const float* __restrict__ w_lin,
                        const float* __restrict__ b_lin, float* __restrict__ out) {
  int g = blockIdx.x;
  int h = threadIdx.x;
  float v = key2f(pooled[g * 64 + h]) * w_lin[h];
  for (int off = 32; off > 0; off >>= 1) v += __shfl_down(v, off, 64);
  if (h == 0) out[g] = v + b_lin[0];
}

extern "C" void kernel_launch(void* const* d_in, const int* in_sizes, int n_in,
                              void* d_out, int out_size, void* d_ws, size_t ws_size,
                              hipStream_t stream) {
  const float* x = (const float*)d_in[0];
  const int* ei = (const int*)d_in[1];
  const int* batch = (const int*)d_in[2];
  const float* w1 = (const float*)d_in[3];
  const float* b1 = (const float*)d_in[4];
  const float* w2 = (const float*)d_in[5];
  const float* b2 = (const float*)d_in[6];
  const float* w3 = (const float*)d_in[7];
  const float* b3 = (const float*)d_in[8];
  const float* g1 = (const float*)d_in[9];
  const float* be1 = (const float*)d_in[10];
  const float* g2 = (const float*)d_in[11];
  const float* be2 = (const float*)d_in[12];
  const float* g3 = (const float*)d_in[13];
  const float* be3 = (const float*)d_in[14];
  const float* w_sc = (const float*)d_in[15];
  const float* b_sc = (const float*)d_in[16];
  const float* w_lin = (const float*)d_in[17];
  const float* b_lin = (const float*)d_in[18];

  int N = in_sizes[0] / 64;
  int E = in_sizes[1] / 2;
  int G = out_size;
  const int* row = ei;
  const int* col = ei + E;

  // chunk shift: 4 chunks cover [0,N)
  int shift = 0;
  while ((4 << shift) < N) shift++;

  int N4 = 4 * N;
  char* p = (char*)d_ws;
  auto carve = [&](size_t bytes) -> void* {
    void* r = (void*)p;
    p += (bytes + 255) & ~(size_t)255;
    return r;
  };
  int* cnt4 = (int*)carve((size_t)N4 * 4);
  float* dis = (float*)carve((size_t)N * 4);
  int* rowptr4 = (int*)carve((size_t)(N4 + 1) * 4);
  int* eslot = (int*)carve((size_t)E * 4);
  int* incl = (int*)carve((size_t)N4 * 4);
  int* bsum = (int*)carve(4096);
  int* bex = (int*)carve(4096);
  int* ccol = (int*)carve((size_t)(E + 64) * 4);   // +64 pad for quartet over-read
  unsigned short* Sbf = (unsigned short*)carve((size_t)N * 64 * 2);
  unsigned short* A02bf = (unsigned short*)carve((size_t)N * 64 * 2);
  unsigned short* Y1bf = (unsigned short*)carve((size_t)N * 64 * 2);
  unsigned short* Y2bf = (unsigned short*)carve((size_t)(N + 1) * 64 * 2);  // row N = 0
  unsigned short* Vbf = (unsigned short*)carve((size_t)(N + 1) * 64 * 2);   // row N = 0
  unsigned short* Cbf = (unsigned short*)carve((size_t)N * 64 * 2);
  float* stats = (float*)carve(256 * 4);  // sums|sumsq
  unsigned* pooled = (unsigned*)carve((size_t)G * 64 * 4);

  int NBG = DIV_UP(N, 128);
  int NC = DIV_UP(E, 2048);
  int npool = G * 64;
  int NPI = DIV_UP(npool, 512);

  int TA = NBG + NC + 1 + NPI;
  int qa = (NBG > 1) ? (TA - 1) / (NBG - 1) : 1;
  if (qa < 1) qa = 1;
  int TB = NBG + NC;
  int qb = (NBG > 1) ? (TB - 1) / (NBG - 1) : 1;
  if (qb < 1) qb = 1;

  // ---- graph build + overlapped independent compute ----
  hipMemsetAsync(cnt4, 0, (size_t)N4 * 4, stream);
  // A: gemmsc || chunked degree count+slot || sentinel zero || poolinit
  k_fused_a<<<TA, 512, 0, stream>>>(x, w_sc, b_sc, Sbf, row, col, cnt4, eslot,
                                    Y2bf, Vbf, pooled, N, E, NBG, NC, npool, qa,
                                    shift);
  int nb = DIV_UP(N4, 1024);
  k_scan1<<<nb, 1024, 0, stream>>>(cnt4, incl, bsum, N4);
  k_scan2<<<1, 512, 0, stream>>>(bsum, bex, nb);
  k_scan3<<<DIV_UP(N4, 256), 256, 0, stream>>>(incl, cnt4, bex, rowptr4, dis,
                                               N, N4, E);
  // B: gemm192(layer0) || atomic-free chunked CSR fill
  k_fused_b<<<TB, 512, 0, stream>>>(x, w1, b1, dis, A02bf, Y1bf, Y2bf,
                                    row, col, rowptr4, eslot, ccol, N, E, NBG, qb,
                                    shift);

  const float* Ws[3] = {w1, w2, w3};
  const float* bs[3] = {b1, b2, b3};
  const float* gs[3] = {g1, g2, g3};
  const float* bes[3] = {be1, be2, be3};

  const int PBLK = 4096;      // 16384 waves; MAXR=7 covers N <= 114688
  const int NWAVE = PBLK * 4;
  for (int l = 0; l < 3; ++l) {
    if (l > 0)
      k_gemm192<<<NBG, 512, 0, stream>>>(Cbf, stats, stats + 64, gs[l - 1], bes[l - 1],
                                         Ws[l], bs[l], dis, A02bf, Y1bf, Y2bf, N);
    // Vbf = bf16( dis * (Y1 + 2*P*Y2) )   (also zeroes stats)
    k_prop4<1><<<PBLK, 256, 0, stream>>>(rowptr4, ccol, dis, Y2bf, Y1bf,
                                         Vbf, nullptr, nullptr, stats, N, NWAVE);
    // Cbf = bf16( (Y0 - Y2) + P*V )  (+ fused BN stats)
    k_prop4<2><<<PBLK, 256, 0, stream>>>(rowptr4, ccol, dis, Vbf, A02bf,
                                         Cbf, stats, stats + 64, nullptr, N, NWAVE);
  }

  k_bnpool<<<DIV_UP(N, 64), 256, 0, stream>>>(Cbf, stats, stats + 64, g3, be3,
                                              Sbf, batch, pooled, N);
  k_final<<<G, 64, 0, stream>>>(pooled, w_lin, b_lin, (float*)d_out);
}

// Round 9
// 651.356 us; speedup vs baseline: 1.7626x; 1.7626x over previous
//
#include <hip/hip_runtime.h>

#define DIV_UP(a,b) (((a)+(b)-1)/(b))

typedef float v4f __attribute__((ext_vector_type(4)));
typedef unsigned short us4 __attribute__((ext_vector_type(4)));
typedef __attribute__((ext_vector_type(8))) short bf16x8;
typedef __attribute__((ext_vector_type(4))) float f32x4;

// ---------- non-temporal helpers ----------
__device__ __forceinline__ float4 ntload4(const float* p) {
  v4f v = __builtin_nontemporal_load((const v4f*)p);
  return make_float4(v.x, v.y, v.z, v.w);
}

// ---------- ordered-uint float max keys ----------
__device__ __forceinline__ unsigned f2key(float f) {
  unsigned u = __float_as_uint(f);
  return (u & 0x80000000u) ? ~u : (u | 0x80000000u);
}
__device__ __forceinline__ float key2f(unsigned u) {
  unsigned b = (u & 0x80000000u) ? (u ^ 0x80000000u) : ~u;
  return __uint_as_float(b);
}

// ---------- bf16 pack/unpack (RNE) ----------
__device__ __forceinline__ unsigned short f2bf(float f) {
  unsigned u = __float_as_uint(f);
  unsigned r = u + 0x7FFFu + ((u >> 16) & 1u);
  return (unsigned short)(r >> 16);
}
__device__ __forceinline__ float bf2f(unsigned short s) {
  return __uint_as_float(((unsigned)s) << 16);
}

// ---------- LDS XOR-swizzle (ushort units, 16B chunks) ----------
__device__ __forceinline__ int swz(int row) {
  return ((row ^ (row >> 3)) & 7) << 3;
}

// ---------- 3-kernel exclusive scan over cnt -> rowptr (+ dis in scan3) -----
__global__ void k_scan1(const int* __restrict__ cnt, int* __restrict__ incl,
                        int* __restrict__ bsum, int N) {
  __shared__ int s[1024];
  int t = threadIdx.x;
  int i = blockIdx.x * 1024 + t;
  int v = (i < N) ? cnt[i] : 0;
  s[t] = v;
  __syncthreads();
  for (int off = 1; off < 1024; off <<= 1) {
    int add = (t >= off) ? s[t - off] : 0;
    __syncthreads();
    s[t] += add;
    __syncthreads();
  }
  if (i < N) incl[i] = s[t];
  if (t == 1023) bsum[blockIdx.x] = s[1023];
}

__global__ void k_scan2(const int* __restrict__ bsum, int* __restrict__ bex, int nb) {
  __shared__ int s[128];
  int t = threadIdx.x;
  if (nb <= 128) {
    int v = (t < nb) ? bsum[t] : 0;
    s[t] = v;
    __syncthreads();
    for (int off = 1; off < 128; off <<= 1) {
      int add = (t >= off) ? s[t - off] : 0;
      __syncthreads();
      s[t] += add;
      __syncthreads();
    }
    if (t < nb) bex[t] = s[t] - v;  // exclusive
  } else if (t == 0) {
    int run = 0;
    for (int b = 0; b < nb; ++b) { bex[b] = run; run += bsum[b]; }
  }
}

__global__ void k_scan3(const int* __restrict__ incl, const int* __restrict__ cnt,
                        const int* __restrict__ bex, int* __restrict__ rowptr,
                        float* __restrict__ dis, int N, int E) {
  int i = blockIdx.x * blockDim.x + threadIdx.x;
  if (i < N) {
    int c = cnt[i];
    rowptr[i] = incl[i] - c + bex[i >> 10];
    dis[i] = (c > 0) ? rsqrtf((float)c) : 0.0f;
  }
  if (i == 0) rowptr[N] = E;
}

// ---------- shortcut GEMM body (MFMA): Sbf = bf16(x @ W_sc + b_sc) ----------
__device__ __forceinline__ void gemmsc_body(unsigned short* wTsc, unsigned short* x16,
                                            int bid,
                                            const float* __restrict__ X,
                                            const float* __restrict__ W,
                                            const float* __restrict__ bias,
                                            unsigned short* __restrict__ Sbf, int N) {
  int tid = threadIdx.x;
  for (int i4 = tid; i4 < 1024; i4 += 512) {
    int d = i4 >> 4, h4 = i4 & 15;
    float4 v = ((const float4*)W)[i4];
    int colb = h4 * 4;
    wTsc[(colb + 0) * 64 + (d ^ swz(colb + 0))] = f2bf(v.x);
    wTsc[(colb + 1) * 64 + (d ^ swz(colb + 1))] = f2bf(v.y);
    wTsc[(colb + 2) * 64 + (d ^ swz(colb + 2))] = f2bf(v.z);
    wTsc[(colb + 3) * 64 + (d ^ swz(colb + 3))] = f2bf(v.w);
  }
  int rowbase = bid * 128;
  for (int i4 = tid; i4 < 2048; i4 += 512) {
    int r = i4 >> 4, c4 = i4 & 15;
    int row = rowbase + r;
    float4 v = (row < N) ? ntload4(X + (size_t)row * 64 + c4 * 4)
                         : make_float4(0.f, 0.f, 0.f, 0.f);
    us4 pk;
    pk.x = f2bf(v.x); pk.y = f2bf(v.y); pk.z = f2bf(v.z); pk.w = f2bf(v.w);
    *(us4*)&x16[r * 64 + ((c4 * 4) ^ swz(r))] = pk;
  }
  __syncthreads();

  int lane = tid & 63;
  int wv = tid >> 6;
  int lo = lane & 15;
  int hi = lane >> 4;

  f32x4 acc[4];
#pragma unroll
  for (int ct = 0; ct < 4; ++ct) acc[ct] = (f32x4){0.f, 0.f, 0.f, 0.f};

#pragma unroll
  for (int ks = 0; ks < 2; ++ks) {
    int ar = wv * 16 + lo;
    bf16x8 af = *(const bf16x8*)&x16[ar * 64 + ((ks * 32 + hi * 8) ^ swz(ar))];
#pragma unroll
    for (int ct = 0; ct < 4; ++ct) {
      int br = ct * 16 + lo;
      bf16x8 bfr = *(const bf16x8*)&wTsc[br * 64 + ((ks * 32 + hi * 8) ^ swz(br))];
      acc[ct] = __builtin_amdgcn_mfma_f32_16x16x32_bf16(af, bfr, acc[ct], 0, 0, 0);
    }
  }

  float bv[4];
#pragma unroll
  for (int ct = 0; ct < 4; ++ct) bv[ct] = bias[ct * 16 + lo];
  int rowb = rowbase + wv * 16 + hi * 4;
#pragma unroll
  for (int reg = 0; reg < 4; ++reg) {
    int row = rowb + reg;
    if (row < N) {
      size_t o = (size_t)row * 64 + lo;
#pragma unroll
      for (int ct = 0; ct < 4; ++ct)
        __builtin_nontemporal_store(f2bf(acc[ct][reg] + bv[ct]), &Sbf[o + ct * 16]);
    }
  }
}

// ---------- shared MFMA tail for the 128x192 layer GEMM ---------------------
__device__ __forceinline__ void mfma192_tail(const unsigned short* x16,
                                             const unsigned short* wT,
                                             int rowbase, int tid,
                                             const float* __restrict__ bias,
                                             const float* __restrict__ dis,
                                             unsigned short* __restrict__ A02bf,
                                             unsigned short* __restrict__ Y1bf,
                                             unsigned short* __restrict__ Y2bf,
                                             int N) {
  int lane = tid & 63;
  int wv = tid >> 6;
  int lo = lane & 15;
  int hi = lane >> 4;

  f32x4 acc[12];
#pragma unroll
  for (int ct = 0; ct < 12; ++ct) acc[ct] = (f32x4){0.f, 0.f, 0.f, 0.f};

#pragma unroll
  for (int ks = 0; ks < 2; ++ks) {
    int ar = wv * 16 + lo;
    bf16x8 af = *(const bf16x8*)&x16[ar * 64 + ((ks * 32 + hi * 8) ^ swz(ar))];
#pragma unroll
    for (int ct = 0; ct < 12; ++ct) {
      int br = ct * 16 + lo;
      bf16x8 bfr = *(const bf16x8*)&wT[br * 64 + ((ks * 32 + hi * 8) ^ swz(br))];
      acc[ct] = __builtin_amdgcn_mfma_f32_16x16x32_bf16(af, bfr, acc[ct], 0, 0, 0);
    }
  }

  float bv[4];
#pragma unroll
  for (int ct = 0; ct < 4; ++ct) bv[ct] = bias[ct * 16 + lo];
  int rowb = rowbase + wv * 16 + hi * 4;
#pragma unroll
  for (int reg = 0; reg < 4; ++reg) {
    int row = rowb + reg;
    if (row < N) {
      float dn = dis[row];
      size_t o = (size_t)row * 64 + lo;
#pragma unroll
      for (int ct = 0; ct < 4; ++ct) {
        float o0 = acc[ct][reg] + bv[ct];
        float o1 = acc[ct + 4][reg];
        float o2 = acc[ct + 8][reg];
        A02bf[o + ct * 16] = f2bf(o0 - o2);
        Y1bf[o + ct * 16] = f2bf(o1);
        Y2bf[o + ct * 16] = f2bf(dn * o2);
      }
    }
  }
}

__device__ __forceinline__ void stage_wT(unsigned short* wT,
                                         const float* __restrict__ W, int tid) {
  for (int i4 = tid; i4 < 3072; i4 += 512) {
    int k3 = i4 >> 10, rem = i4 & 1023;
    int d = rem >> 4, h4 = rem & 15;
    float4 v = ((const float4*)W)[i4];
    int colb = k3 * 64 + h4 * 4;
    wT[(colb + 0) * 64 + (d ^ swz(colb + 0))] = f2bf(v.x);
    wT[(colb + 1) * 64 + (d ^ swz(colb + 1))] = f2bf(v.y);
    wT[(colb + 2) * 64 + (d ^ swz(colb + 2))] = f2bf(v.z);
    wT[(colb + 3) * 64 + (d ^ swz(colb + 3))] = f2bf(v.w);
  }
}

__device__ __forceinline__ void gemm192_l0_body(unsigned short* x16, unsigned short* wT,
                                                int bid,
                                                const float* __restrict__ X,
                                                const float* __restrict__ W,
                                                const float* __restrict__ bias,
                                                const float* __restrict__ dis,
                                                unsigned short* __restrict__ A02bf,
                                                unsigned short* __restrict__ Y1bf,
                                                unsigned short* __restrict__ Y2bf,
                                                int N) {
  int tid = threadIdx.x;
  stage_wT(wT, W, tid);
  int rowbase = bid * 128;
  for (int i4 = tid; i4 < 2048; i4 += 512) {
    int r = i4 >> 4, c4 = i4 & 15;
    int row = rowbase + r;
    float4 v = (row < N) ? ntload4(X + (size_t)row * 64 + c4 * 4)
                         : make_float4(0.f, 0.f, 0.f, 0.f);
    us4 pk;
    pk.x = f2bf(v.x); pk.y = f2bf(v.y); pk.z = f2bf(v.z); pk.w = f2bf(v.w);
    *(us4*)&x16[r * 64 + ((c4 * 4) ^ swz(r))] = pk;
  }
  __syncthreads();
  mfma192_tail(x16, wT, rowbase, tid, bias, dis, A02bf, Y1bf, Y2bf, N);
}

// ---------- fused A: gemmsc | count+slot | sentinel | poolinit --------------
// Count role records eslot[e] = within-row slot (atomic return). 1.6M atomics
// at the measured ~8/cycle device atomic ceiling => ~84us floor for this role.
__global__ __launch_bounds__(512) void k_fused_a(const float* __restrict__ X,
                                                 const float* __restrict__ W,
                                                 const float* __restrict__ bias,
                                                 unsigned short* __restrict__ Sbf,
                                                 const int* __restrict__ row,
                                                 int* __restrict__ cnt,
                                                 int* __restrict__ eslot,
                                                 unsigned short* __restrict__ Y2bf,
                                                 unsigned short* __restrict__ Vbf,
                                                 unsigned* __restrict__ pooled,
                                                 int N, int E, int NBG, int NC,
                                                 int npool, int q) {
  __shared__ unsigned short wTsc[64 * 64];   // 8 KB
  __shared__ unsigned short x16a[128 * 64];  // 16 KB
  int bid = blockIdx.x;
  bool isg = (bid % q == 0) && (bid / q < NBG);
  if (isg) {
    gemmsc_body(wTsc, x16a, bid / q, X, W, bias, Sbf, N);
  } else {
    int before = min((bid + q - 1) / q, NBG);
    int oi = bid - before;
    if (oi < NC) {
      int e0 = oi * 2048 + threadIdx.x;
      int r[4], idx[4];
#pragma unroll
      for (int k = 0; k < 4; ++k) {
        int e = e0 + k * 512;
        if (e < E) r[k] = row[e];
      }
#pragma unroll
      for (int k = 0; k < 4; ++k) {
        int e = e0 + k * 512;
        if (e < E) idx[k] = atomicAdd(&cnt[r[k]], 1);
      }
#pragma unroll
      for (int k = 0; k < 4; ++k) {
        int e = e0 + k * 512;
        if (e < E) __builtin_nontemporal_store(idx[k], &eslot[e]);
      }
    } else if (oi == NC) {
      if (threadIdx.x < 64) {
        Y2bf[(size_t)N * 64 + threadIdx.x] = 0;
        Vbf[(size_t)N * 64 + threadIdx.x] = 0;
      }
    } else {
      int i = (oi - NC - 1) * 512 + threadIdx.x;
      if (i < npool) pooled[i] = 0x007FFFFFu;  // key(-inf)
    }
  }
}

// ---------- fused B: gemm192(l0, MFMA) | atomic-free fill ------------------
__global__ __launch_bounds__(512) void k_fused_b(const float* __restrict__ X,
                                                 const float* __restrict__ W,
                                                 const float* __restrict__ bias,
                                                 const float* __restrict__ dis,
                                                 unsigned short* __restrict__ A02bf,
                                                 unsigned short* __restrict__ Y1bf,
                                                 unsigned short* __restrict__ Y2bf,
                                                 const int* __restrict__ row,
                                                 const int* __restrict__ col,
                                                 const int* __restrict__ rowptr,
                                                 const int* __restrict__ eslot,
                                                 int* __restrict__ ccol,
                                                 int N, int E, int NBG, int q) {
  __shared__ unsigned short x16b[128 * 64];  // 16 KB
  __shared__ unsigned short wTb[192 * 64];   // 24 KB
  int bid = blockIdx.x;
  bool isg = (bid % q == 0) && (bid / q < NBG);
  if (isg) {
    gemm192_l0_body(x16b, wTb, bid / q, X, W, bias, dis, A02bf, Y1bf, Y2bf, N);
  } else {
    int before = min((bid + q - 1) / q, NBG);
    int oi = bid - before;
    int e0 = oi * 2048 + threadIdx.x;
    int r[4], c[4], sl[4], base[4];
#pragma unroll
    for (int k = 0; k < 4; ++k) {
      int e = e0 + k * 512;
      if (e < E) { r[k] = row[e]; c[k] = col[e]; sl[k] = eslot[e]; }
    }
#pragma unroll
    for (int k = 0; k < 4; ++k) {
      int e = e0 + k * 512;
      if (e < E) base[k] = rowptr[r[k]];
    }
#pragma unroll
    for (int k = 0; k < 4; ++k) {
      int e = e0 + k * 512;
      if (e < E) ccol[base[k] + sl[k]] = c[k];
    }
  }
}

// ---------- layer GEMM (l>=1): MFMA, bf16 input + in-block BN ---------------
__global__ __launch_bounds__(512) void k_gemm192(
    const unsigned short* __restrict__ Cbf,
    const float* __restrict__ sums, const float* __restrict__ sumsq,
    const float* __restrict__ g, const float* __restrict__ be,
    const float* __restrict__ W, const float* __restrict__ bias,
    const float* __restrict__ dis,
    unsigned short* __restrict__ A02bf, unsigned short* __restrict__ Y1bf,
    unsigned short* __restrict__ Y2bf, int N) {
  __shared__ unsigned short x16[128 * 64];
  __shared__ unsigned short wT[192 * 64];
  int bid = blockIdx.x;
  int tid = threadIdx.x;

  int cb = (tid & 15) * 4;
  float inv_n = 1.0f / (float)N;
  float scv[4], shv[4];
#pragma unroll
  for (int k = 0; k < 4; ++k) {
    float mu = sums[cb + k] * inv_n;
    float var = sumsq[cb + k] * inv_n - mu * mu;
    float sc = g[cb + k] * rsqrtf(var + 1e-5f);
    scv[k] = sc;
    shv[k] = be[cb + k] - mu * sc;
  }

  stage_wT(wT, W, tid);

  int rowbase = bid * 128;
  for (int i4 = tid; i4 < 2048; i4 += 512) {
    int r = i4 >> 4, c4 = i4 & 15;
    int row = rowbase + r;
    float vx, vy, vz, vw;
    if (row < N) {
      unsigned long long u =
          *(const unsigned long long*)(Cbf + (size_t)row * 64 + c4 * 4);
      vx = bf2f((unsigned short)(u & 0xffffu));
      vy = bf2f((unsigned short)((u >> 16) & 0xffffu));
      vz = bf2f((unsigned short)((u >> 32) & 0xffffu));
      vw = bf2f((unsigned short)(u >> 48));
    } else {
      vx = vy = vz = vw = 0.f;
    }
    float a = vx * scv[0] + shv[0];
    float b = vy * scv[1] + shv[1];
    float c = vz * scv[2] + shv[2];
    float d = vw * scv[3] + shv[3];
    a = (a > 0.f) ? a : 0.01f * a;
    b = (b > 0.f) ? b : 0.01f * b;
    c = (c > 0.f) ? c : 0.01f * c;
    d = (d > 0.f) ? d : 0.01f * d;
    us4 pk;
    pk.x = f2bf(a); pk.y = f2bf(b); pk.z = f2bf(c); pk.w = f2bf(d);
    *(us4*)&x16[r * 64 + ((c4 * 4) ^ swz(r))] = pk;
  }
  __syncthreads();

  mfma192_tail(x16, wT, rowbase, tid, bias, dis, A02bf, Y1bf, Y2bf, N);
}

// ---------- prop v10: octet dwordx4 gathers + 1-row-ahead pipeline ---------
// Per 8-col step: each lane's octet (oct = lane>>3) loads its col's ccol
// directly (8-lane broadcast), then ONE dwordx4 gather fetches 8 full rows
// (64 lanes x 16B = 8 x 128B random lines in flight per instruction — 2x the
// v8 dwordx2 scheme; round-8 falsified chunking and showed prop time is
// MLP-sensitive at constant FETCH). Lane owns channels 8*s8..8*s8+7.
// Octet partials merged via shfl_xor(8,16,32). Epilogue I/O 16B on lanes 0-7.
// MODE 1: Vbf[n] = bf16( dis[n]*(Y1[n] - 2*dis[n]*acc) ); zeroes stats
// MODE 2: Cbf[n] = bf16( A02[n] - dis[n]*acc )  (+ fused BN stats)
template <int MODE>
__global__ __launch_bounds__(256) void k_prop4(const int* __restrict__ rowptr,
                                               const int* __restrict__ ccol,
                                               const float* __restrict__ dis,
                                               const unsigned short* __restrict__ zbf,
                                               const unsigned short* __restrict__ inAbf,
                                               unsigned short* __restrict__ outbf,
                                               float* __restrict__ sums,
                                               float* __restrict__ sumsq,
                                               float* __restrict__ zstats,
                                               int N, int nwaves) {
  if (MODE == 1 && blockIdx.x == 0 && threadIdx.x < 128) zstats[threadIdx.x] = 0.f;
  int gw = blockIdx.x * 4 + (threadIdx.x >> 6);
  int lane = threadIdx.x & 63;
  int wid = threadIdx.x >> 6;
  int oct = lane >> 3;  // octet 0..7: handles col j+oct of each 8-col step
  int s8 = lane & 7;    // owns channels 8*s8..8*s8+7 (16 B of a row)
  float st[8], st2[8];
#pragma unroll
  for (int k = 0; k < 8; ++k) { st[k] = 0.f; st2[k] = 0.f; }

  int n = gw, beg = 0, end = 0, cl = 0;
  if (n < N) {
    beg = rowptr[n];
    end = rowptr[n + 1];
    cl = ccol[beg + oct];  // ccol padded by 64 -> safe
  }
  while (n < N) {
    int nn = n + nwaves;
    int begn = 0, endn = 0;
    if (nn < N) {  // prefetch next row's descriptor (overlaps gathers)
      begn = rowptr[nn];
      endn = rowptr[nn + 1];
    }
    float dn = dis[n];  // hoisted: overlaps gathers
    size_t o = (size_t)n * 64 + s8 * 8;  // ushort offset
    uint4 av = make_uint4(0, 0, 0, 0);
    if (oct == 0) av = *(const uint4*)(inAbf + o);  // hoisted
    float a[8];
#pragma unroll
    for (int k = 0; k < 8; ++k) a[k] = 0.f;
    {  // step 0 from prefetched cl
      int c = (beg + oct < end) ? cl : N;  // sentinel row N is zeroed
      uint4 zv = *(const uint4*)(zbf + (size_t)c * 64 + s8 * 8);
      a[0] += __uint_as_float(zv.x << 16);
      a[1] += __uint_as_float(zv.x & 0xFFFF0000u);
      a[2] += __uint_as_float(zv.y << 16);
      a[3] += __uint_as_float(zv.y & 0xFFFF0000u);
      a[4] += __uint_as_float(zv.z << 16);
      a[5] += __uint_as_float(zv.z & 0xFFFF0000u);
      a[6] += __uint_as_float(zv.w << 16);
      a[7] += __uint_as_float(zv.w & 0xFFFF0000u);
    }
    for (int j = beg + 8; j < end; j += 8) {
      int jo = j + oct;
      int c = ccol[jo];
      c = (jo < end) ? c : N;
      uint4 zv = *(const uint4*)(zbf + (size_t)c * 64 + s8 * 8);
      a[0] += __uint_as_float(zv.x << 16);
      a[1] += __uint_as_float(zv.x & 0xFFFF0000u);
      a[2] += __uint_as_float(zv.y << 16);
      a[3] += __uint_as_float(zv.y & 0xFFFF0000u);
      a[4] += __uint_as_float(zv.z << 16);
      a[5] += __uint_as_float(zv.z & 0xFFFF0000u);
      a[6] += __uint_as_float(zv.w << 16);
      a[7] += __uint_as_float(zv.w & 0xFFFF0000u);
    }
    int cln = 0;
    if (nn < N) cln = ccol[begn + oct];  // prefetch: overlaps merge+epilogue
    // merge octet partials: every lane ends with the full neighbor sum
#pragma unroll
    for (int k = 0; k < 8; ++k) {
      a[k] += __shfl_xor(a[k], 8, 64);
      a[k] += __shfl_xor(a[k], 16, 64);
      a[k] += __shfl_xor(a[k], 32, 64);
    }
    if (oct == 0) {
      float x0 = __uint_as_float(av.x << 16);
      float x1 = __uint_as_float(av.x & 0xFFFF0000u);
      float x2 = __uint_as_float(av.y << 16);
      float x3 = __uint_as_float(av.y & 0xFFFF0000u);
      float x4 = __uint_as_float(av.z << 16);
      float x5 = __uint_as_float(av.z & 0xFFFF0000u);
      float x6 = __uint_as_float(av.w << 16);
      float x7 = __uint_as_float(av.w & 0xFFFF0000u);
      float v0, v1, v2, v3, v4, v5, v6, v7;
      if (MODE == 1) {
        v0 = dn * (x0 - 2.f * dn * a[0]);
        v1 = dn * (x1 - 2.f * dn * a[1]);
        v2 = dn * (x2 - 2.f * dn * a[2]);
        v3 = dn * (x3 - 2.f * dn * a[3]);
        v4 = dn * (x4 - 2.f * dn * a[4]);
        v5 = dn * (x5 - 2.f * dn * a[5]);
        v6 = dn * (x6 - 2.f * dn * a[6]);
        v7 = dn * (x7 - 2.f * dn * a[7]);
      } else {
        v0 = x0 - dn * a[0];
        v1 = x1 - dn * a[1];
        v2 = x2 - dn * a[2];
        v3 = x3 - dn * a[3];
        v4 = x4 - dn * a[4];
        v5 = x5 - dn * a[5];
        v6 = x6 - dn * a[6];
        v7 = x7 - dn * a[7];
        st[0] += v0; st2[0] = fmaf(v0, v0, st2[0]);
        st[1] += v1; st2[1] = fmaf(v1, v1, st2[1]);
        st[2] += v2; st2[2] = fmaf(v2, v2, st2[2]);
        st[3] += v3; st2[3] = fmaf(v3, v3, st2[3]);
        st[4] += v4; st2[4] = fmaf(v4, v4, st2[4]);
        st[5] += v5; st2[5] = fmaf(v5, v5, st2[5]);
        st[6] += v6; st2[6] = fmaf(v6, v6, st2[6]);
        st[7] += v7; st2[7] = fmaf(v7, v7, st2[7]);
      }
      uint4 pk;
      pk.x = (unsigned)f2bf(v0) | ((unsigned)f2bf(v1) << 16);
      pk.y = (unsigned)f2bf(v2) | ((unsigned)f2bf(v3) << 16);
      pk.z = (unsigned)f2bf(v4) | ((unsigned)f2bf(v5) << 16);
      pk.w = (unsigned)f2bf(v6) | ((unsigned)f2bf(v7) << 16);
      *(uint4*)(outbf + o) = pk;
    }
    n = nn; beg = begn; end = endn; cl = cln;
  }
  if (MODE == 2) {
    __shared__ float red[2][4][64];
    if (oct == 0) {
#pragma unroll
      for (int k = 0; k < 8; ++k) {
        red[0][wid][8 * s8 + k] = st[k];
        red[1][wid][8 * s8 + k] = st2[k];
      }
    }
    __syncthreads();
    if (wid == 0) {
      float a = red[0][0][lane] + red[0][1][lane] + red[0][2][lane] + red[0][3][lane];
      float b = red[1][0][lane] + red[1][1][lane] + red[1][2][lane] + red[1][3][lane];
      atomicAdd(&sums[lane], a);
      atomicAdd(&sumsq[lane], b);
    }
  }
}

// fused: h = lrelu(bn(Cbf)) + Sbf; segment-max into pooled (coefs in-block)
__global__ void k_bnpool(const unsigned short* __restrict__ Cbf,
                         const float* __restrict__ sums, const float* __restrict__ sumsq,
                         const float* __restrict__ g, const float* __restrict__ be,
                         const unsigned short* __restrict__ Sbf,
                         const int* __restrict__ batch,
                         unsigned* __restrict__ pooled, int N) {
  __shared__ float sc_s[64], sh_s[64];
  if (threadIdx.x < 64) {
    int h = threadIdx.x;
    float inv_n = 1.0f / (float)N;
    float mu = sums[h] * inv_n;
    float var = sumsq[h] * inv_n - mu * mu;
    float sc = g[h] * rsqrtf(var + 1e-5f);
    sc_s[h] = sc;
    sh_s[h] = be[h] - mu * sc;
  }
  __syncthreads();
  int t = threadIdx.x;
  int h = t & 63;
  int rsub = t >> 6;
  int base = blockIdx.x * 64;
  float sc = sc_s[h], sh = sh_s[h];
  int cur_g = -1;
  unsigned best = 0;
  for (int i = 0; i < 16; ++i) {
    int n = base + rsub + 4 * i;
    if (n >= N) break;
    int gidx = batch[n];
    size_t o = (size_t)n * 64 + h;
    float a = bf2f(__builtin_nontemporal_load(&Cbf[o])) * sc + sh;
    a = (a > 0.f) ? a : 0.01f * a;
    a += bf2f(__builtin_nontemporal_load(&Sbf[o]));
    unsigned k = f2key(a);
    if (gidx != cur_g) {
      if (cur_g >= 0) atomicMax(&pooled[cur_g * 64 + h], best);
      cur_g = gidx;
      best = k;
    } else {
      best = max(best, k);
    }
  }
  if (cur_g >= 0) atomicMax(&pooled[cur_g * 64 + h], best);
}

__global__ void k_final(const unsigned* __restrict__ pooled, const float* __restrict__ w_lin,
                        const float* __restrict__ b_lin, float* __restrict__ out) {
  int g = blockIdx.x;
  int h = threadIdx.x;
  float v = key2f(pooled[g * 64 + h]) * w_lin[h];
  for (int off = 32; off > 0; off >>= 1) v += __shfl_down(v, off, 64);
  if (h == 0) out[g] = v + b_lin[0];
}

extern "C" void kernel_launch(void* const* d_in, const int* in_sizes, int n_in,
                              void* d_out, int out_size, void* d_ws, size_t ws_size,
                              hipStream_t stream) {
  const float* x = (const float*)d_in[0];
  const int* ei = (const int*)d_in[1];
  const int* batch = (const int*)d_in[2];
  const float* w1 = (const float*)d_in[3];
  const float* b1 = (const float*)d_in[4];
  const float* w2 = (const float*)d_in[5];
  const float* b2 = (const float*)d_in[6];
  const float* w3 = (const float*)d_in[7];
  const float* b3 = (const float*)d_in[8];
  const float* g1 = (const float*)d_in[9];
  const float* be1 = (const float*)d_in[10];
  const float* g2 = (const float*)d_in[11];
  const float* be2 = (const float*)d_in[12];
  const float* g3 = (const float*)d_in[13];
  const float* be3 = (const float*)d_in[14];
  const float* w_sc = (const float*)d_in[15];
  const float* b_sc = (const float*)d_in[16];
  const float* w_lin = (const float*)d_in[17];
  const float* b_lin = (const float*)d_in[18];

  int N = in_sizes[0] / 64;
  int E = in_sizes[1] / 2;
  int G = out_size;
  const int* row = ei;
  const int* col = ei + E;

  char* p = (char*)d_ws;
  auto carve = [&](size_t bytes) -> void* {
    void* r = (void*)p;
    p += (bytes + 255) & ~(size_t)255;
    return r;
  };
  int* cnt = (int*)carve((size_t)N * 4);
  float* dis = (float*)carve((size_t)N * 4);
  int* rowptr = (int*)carve((size_t)(N + 1) * 4);
  int* eslot = (int*)carve((size_t)E * 4);
  int* incl = (int*)carve((size_t)N * 4);
  int* bsum = (int*)carve(1024);
  int* bex = (int*)carve(1024);
  int* ccol = (int*)carve((size_t)(E + 64) * 4);   // +64 pad for octet over-read
  unsigned short* Sbf = (unsigned short*)carve((size_t)N * 64 * 2);
  unsigned short* A02bf = (unsigned short*)carve((size_t)N * 64 * 2);
  unsigned short* Y1bf = (unsigned short*)carve((size_t)N * 64 * 2);
  unsigned short* Y2bf = (unsigned short*)carve((size_t)(N + 1) * 64 * 2);  // row N = 0
  unsigned short* Vbf = (unsigned short*)carve((size_t)(N + 1) * 64 * 2);   // row N = 0
  unsigned short* Cbf = (unsigned short*)carve((size_t)N * 64 * 2);
  float* stats = (float*)carve(256 * 4);  // sums|sumsq
  unsigned* pooled = (unsigned*)carve((size_t)G * 64 * 4);

  int NBG = DIV_UP(N, 128);
  int NC = DIV_UP(E, 2048);
  int npool = G * 64;
  int NPI = DIV_UP(npool, 512);

  int TA = NBG + NC + 1 + NPI;
  int qa = (NBG > 1) ? (TA - 1) / (NBG - 1) : 1;
  if (qa < 1) qa = 1;
  int TB = NBG + NC;
  int qb = (NBG > 1) ? (TB - 1) / (NBG - 1) : 1;
  if (qb < 1) qb = 1;

  // ---- graph build + overlapped independent compute ----
  hipMemsetAsync(cnt, 0, (size_t)N * 4, stream);
  // A: gemmsc || degree count+slot || sentinel zero || poolinit
  k_fused_a<<<TA, 512, 0, stream>>>(x, w_sc, b_sc, Sbf, row, cnt, eslot,
                                    Y2bf, Vbf, pooled, N, E, NBG, NC, npool, qa);
  int nb = DIV_UP(N, 1024);
  k_scan1<<<nb, 1024, 0, stream>>>(cnt, incl, bsum, N);
  k_scan2<<<1, 128, 0, stream>>>(bsum, bex, nb);
  k_scan3<<<DIV_UP(N, 256), 256, 0, stream>>>(incl, cnt, bex, rowptr, dis, N, E);
  // B: gemm192(layer0) || atomic-free CSR fill
  k_fused_b<<<TB, 512, 0, stream>>>(x, w1, b1, dis, A02bf, Y1bf, Y2bf,
                                    row, col, rowptr, eslot, ccol, N, E, NBG, qb);

  const float* Ws[3] = {w1, w2, w3};
  const float* bs[3] = {b1, b2, b3};
  const float* gs[3] = {g1, g2, g3};
  const float* bes[3] = {be1, be2, be3};

  const int PBLK = 2048;      // persistent blocks, 4 waves each (all resident)
  const int NWAVE = PBLK * 4;
  for (int l = 0; l < 3; ++l) {
    if (l > 0)
      k_gemm192<<<NBG, 512, 0, stream>>>(Cbf, stats, stats + 64, gs[l - 1], bes[l - 1],
                                         Ws[l], bs[l], dis, A02bf, Y1bf, Y2bf, N);
    // Vbf = bf16( dis * (Y1 + 2*P*Y2) )   (also zeroes stats)
    k_prop4<1><<<PBLK, 256, 0, stream>>>(rowptr, ccol, dis, Y2bf, Y1bf,
                                         Vbf, nullptr, nullptr, stats, N, NWAVE);
    // Cbf = bf16( (Y0 - Y2) + P*V )  (+ fused BN stats)
    k_prop4<2><<<PBLK, 256, 0, stream>>>(rowptr, ccol, dis, Vbf, A02bf,
                                         Cbf, stats, stats + 64, nullptr, N, NWAVE);
  }

  k_bnpool<<<DIV_UP(N, 64), 256, 0, stream>>>(Cbf, stats, stats + 64, g3, be3,
                                              Sbf, batch, pooled, N);
  k_final<<<G, 64, 0, stream>>>(pooled, w_lin, b_lin, (float*)d_out);
}